// Round 9
// baseline (171.852 us; speedup 1.0000x reference)
//
#include <hip/hip_runtime.h>
#include <hip/hip_bf16.h>

// Swin window attention, fully fused, bf16-MFMA, head-split-wave version.
// Wave w owns HEAD w end-to-end: q/k/v for head w (32 dims, all 64 tokens)
// computed and kept IN REGISTERS; attention fully in-wave (no LDS, no barrier).
// Only the attention output crosses waves (proj contracts all 128 dims):
// one 17.4 KB LDS buffer + ONE barrier.
//   phase1: per head: q,k (transposed GEMM) + v (NON-transposed, operand duality:
//           same xa/wf registers, swapped MFMA operands) -> packed D-frags in regs.
//           24 weight-frag loads / 96 MFMAs per wave (4 MFMA/load; round 8 had 1).
//   phase2: kf/vf/qf via validated repack (shfl); S^T=K(A).Q^T(B); +bias+mask;
//           in-lane softmax; pa=repack(pkv); ao^T=V^T(A).P^T(B) -> b64 LDS store.
//   phase3: out^T = Wp^T(A) . ao^T(B), B-frag read straight from ao_lds (duality);
//           coalesced f32x4 stores.
// MFMA 16x16x32 bf16 layouts (validated end-to-end rounds 3/5/6/8):
//   src0 A: lane holds A[lane&15][(lane>>4)*8+j]
//   src1 B: lane holds B[(lane>>4)*8+j][lane&15]
//   D:      lane holds D[(lane>>4)*4+r][lane&15]
// repack (validated r5-r8): input = D-packed pairs (4 axisA values at fixed
// axisB=f(lq), tiles X=0,1); output elem j = M[axisA=lg*8+j][axisB=lq].

typedef __attribute__((ext_vector_type(8))) short bf16x8;
typedef __attribute__((ext_vector_type(4))) float f32x4;

#define NTOK  49
#define CDIM  128
#define NWIN  256
#define LDA   136     // ao_lds stride (shorts); 272 B rows -> 2-way-free banks
#define SCALE 0.17677669529663687f
#define PROJ_WOFF 49152   // shorts: 96 frags * 512

static __device__ __forceinline__ unsigned pk2(float a, float b) {
    __hip_bfloat162 h = __float22bfloat162_rn(make_float2(a, b));  // low = a, high = b, RNE
    unsigned u; __builtin_memcpy(&u, &h, 4); return u;
}
static __device__ __forceinline__ short bf1(float a) {
    __hip_bfloat16 h = __float2bfloat16(a);
    unsigned short u; __builtin_memcpy(&u, &h, 2); return (short)u;
}
static __device__ __forceinline__ bf16x8 repack(unsigned p00, unsigned p01,
                                                unsigned p10, unsigned p11,
                                                int src0, int src1, bool hi) {
    union { bf16x8 v; unsigned u[4]; } t;
    unsigned a0, a1;
    a0 = __shfl((int)p00, src0, 64); a1 = __shfl((int)p10, src0, 64); t.u[0] = hi ? a1 : a0;
    a0 = __shfl((int)p01, src0, 64); a1 = __shfl((int)p11, src0, 64); t.u[1] = hi ? a1 : a0;
    a0 = __shfl((int)p00, src1, 64); a1 = __shfl((int)p10, src1, 64); t.u[2] = hi ? a1 : a0;
    a0 = __shfl((int)p01, src1, 64); a1 = __shfl((int)p11, src1, 64); t.u[3] = hi ? a1 : a0;
    return t.v;
}

// ---- weight pre-swizzle: per-tile fragments = A-frags of W^T (== B-frags of W) ----
__global__ void prep_w(const float* __restrict__ qkv_w,
                       const float* __restrict__ proj_w,
                       short* __restrict__ wb) {
    const int fid = blockIdx.x;     // 0..127 (96 qkv + 32 proj)
    const int l   = threadIdx.x;    // 0..63
    const int lq = l & 15, lg = l >> 4;
    bf16x8 v;
    if (fid < 96) {
        const int nt = fid >> 2, kk = fid & 3;
        #pragma unroll
        for (int j = 0; j < 8; ++j)
            v[j] = bf1(qkv_w[(kk*32 + lg*8 + j)*384 + nt*16 + lq]);
        *(bf16x8*)(wb + fid*512 + l*8) = v;
    } else {
        const int f2 = fid - 96;
        const int nt = f2 >> 2, kk = f2 & 3;
        #pragma unroll
        for (int j = 0; j < 8; ++j)
            v[j] = bf1(proj_w[(kk*32 + lg*8 + j)*128 + nt*16 + lq]);
        *(bf16x8*)(wb + PROJ_WOFF + f2*512 + l*8) = v;
    }
}

__global__ __launch_bounds__(256, 2)
void win_attn(const float* __restrict__ x,
              const float* __restrict__ mask,
              const float* __restrict__ qkv_b,
              const float* __restrict__ proj_b,
              const float* __restrict__ bias_table,
              const short* __restrict__ wb,
              float* __restrict__ out) {
    __shared__ __align__(16) short ao_lds[64 * LDA];   // 17408 B -- the ONLY LDS

    const int b   = blockIdx.x;
    const int tid = threadIdx.x;
    const int l   = tid & 63;
    const int wv  = tid >> 6;       // wave index == HEAD index
    const int lq  = l & 15, lg = l >> 4;

    // ---- Phase 0: x^T B-frags for ALL 4 token tiles (A-frags of X by duality) ----
    const float* xb = x + (size_t)b * (NTOK * CDIM);
    bf16x8 xa[4][4];
    #pragma unroll
    for (int mt = 0; mt < 4; ++mt) {
        int row = mt*16 + lq; if (row > 48) row = 48;
        const float* pr = xb + row*CDIM + lg*8;
        #pragma unroll
        for (int kk = 0; kk < 4; ++kk) {
            float4 f0 = *(const float4*)(pr + kk*32);
            float4 f1 = *(const float4*)(pr + kk*32 + 4);
            union { bf16x8 v; unsigned u[4]; } t;
            t.u[0] = pk2(f0.x, f0.y);
            t.u[1] = pk2(f0.z, f0.w);
            t.u[2] = pk2(f1.x, f1.y);
            t.u[3] = pk2(f1.z, f1.w);
            xa[mt][kk] = t.v;
        }
    }

    // ---- Phase 1: q,k,v for head wv, all 64 tokens, registers only ----
    // qpk/kpk: transposed D packed along wcols (axisA=dim) at fixed tok (axisB).
    // vpk: NON-transposed D packed along toks (axisA=tok) at fixed dim (axisB).
    unsigned qpk[2][4][2], kpk[2][4][2], vpk[2][4][2];
    #pragma unroll
    for (int t = 0; t < 2; ++t) {
        {   // q tile (transposed: D = Wq^T(A) . x^T(B))
            const int nt = 2*wv + t;
            bf16x8 wf[4];
            #pragma unroll
            for (int kk = 0; kk < 4; ++kk)
                wf[kk] = *(const bf16x8*)(wb + (nt*4 + kk)*512 + l*8);
            const f32x4 bia = *(const f32x4*)(qkv_b + nt*16 + lg*4);
            f32x4 acc[4];
            #pragma unroll
            for (int mt = 0; mt < 4; ++mt) acc[mt] = bia;
            #pragma unroll
            for (int kk = 0; kk < 4; ++kk)
                #pragma unroll
                for (int mt = 0; mt < 4; ++mt)
                    acc[mt] = __builtin_amdgcn_mfma_f32_16x16x32_bf16(wf[kk], xa[mt][kk], acc[mt], 0, 0, 0);
            #pragma unroll
            for (int mt = 0; mt < 4; ++mt) {
                qpk[t][mt][0] = pk2(acc[mt][0]*SCALE, acc[mt][1]*SCALE);
                qpk[t][mt][1] = pk2(acc[mt][2]*SCALE, acc[mt][3]*SCALE);
            }
        }
        {   // k tile (transposed)
            const int nt = 8 + 2*wv + t;
            bf16x8 wf[4];
            #pragma unroll
            for (int kk = 0; kk < 4; ++kk)
                wf[kk] = *(const bf16x8*)(wb + (nt*4 + kk)*512 + l*8);
            const f32x4 bia = *(const f32x4*)(qkv_b + nt*16 + lg*4);
            f32x4 acc[4];
            #pragma unroll
            for (int mt = 0; mt < 4; ++mt) acc[mt] = bia;
            #pragma unroll
            for (int kk = 0; kk < 4; ++kk)
                #pragma unroll
                for (int mt = 0; mt < 4; ++mt)
                    acc[mt] = __builtin_amdgcn_mfma_f32_16x16x32_bf16(wf[kk], xa[mt][kk], acc[mt], 0, 0, 0);
            #pragma unroll
            for (int mt = 0; mt < 4; ++mt) {
                kpk[t][mt][0] = pk2(acc[mt][0], acc[mt][1]);
                kpk[t][mt][1] = pk2(acc[mt][2], acc[mt][3]);
            }
        }
        {   // v tile (NON-transposed: D = X(A) . Wv(B); same registers, swapped operands)
            const int nt = 16 + 2*wv + t;
            bf16x8 wf[4];
            #pragma unroll
            for (int kk = 0; kk < 4; ++kk)
                wf[kk] = *(const bf16x8*)(wb + (nt*4 + kk)*512 + l*8);
            const float bv = qkv_b[nt*16 + lq];          // per-dim bias (D col = dim)
            f32x4 acc[4];
            #pragma unroll
            for (int mt = 0; mt < 4; ++mt) acc[mt] = (f32x4){bv, bv, bv, bv};
            #pragma unroll
            for (int kk = 0; kk < 4; ++kk)
                #pragma unroll
                for (int mt = 0; mt < 4; ++mt)
                    acc[mt] = __builtin_amdgcn_mfma_f32_16x16x32_bf16(xa[mt][kk], wf[kk], acc[mt], 0, 0, 0);
            #pragma unroll
            for (int mt = 0; mt < 4; ++mt) {
                vpk[t][mt][0] = pk2(acc[mt][0], acc[mt][1]);   // packs toks at fixed dim
                vpk[t][mt][1] = pk2(acc[mt][2], acc[mt][3]);
            }
        }
    }

    // ---- Phase 1c: bias+mask for head wv (wave-uniform head -> scalar gather) ----
    const float* mwin = mask + (size_t)(b & (NWIN - 1)) * (NTOK * NTOK);
    unsigned bmpk[4][4][2];
    #pragma unroll
    for (int mtq = 0; mtq < 4; ++mtq) {
        const int qtok = mtq*16 + lq;
        #pragma unroll
        for (int mtk = 0; mtk < 4; ++mtk) {
            float bm[4];
            #pragma unroll
            for (int r = 0; r < 4; ++r) {
                const int kt = mtk*16 + lg*4 + r;
                bm[r] = -1e30f;
                if (qtok < NTOK && kt < NTOK) {
                    const int ridx = (qtok/7 - kt/7 + 6)*13 + (qtok%7 - kt%7 + 6);
                    bm[r] = bias_table[ridx*4 + wv] + mwin[qtok*NTOK + kt];
                }
            }
            bmpk[mtq][mtk][0] = pk2(bm[0], bm[1]);
            bmpk[mtq][mtk][1] = pk2(bm[2], bm[3]);
        }
    }

    // ---- Phase 2: head-wv attention, fully in-wave ----
    const int src0 = lq + 16*((2*lg + 0) & 3);
    const int src1 = lq + 16*((2*lg + 1) & 3);
    const bool hi  = (lg >> 1);

    // K A-frags (axisA=dim tiles 0,1 -> kcol=lg*8+j in 0..31; axisB=ktok=lq)
    bf16x8 kf[4];
    #pragma unroll
    for (int mtk = 0; mtk < 4; ++mtk)
        kf[mtk] = repack(kpk[0][mtk][0], kpk[0][mtk][1], kpk[1][mtk][0], kpk[1][mtk][1],
                         src0, src1, hi);
    // V^T A-frags (axisA=tok tiles (2c,2c+1) -> vtok=c*32+lg*8+j; axisB=dim=lq)
    bf16x8 vf[2][2];
    #pragma unroll
    for (int dv = 0; dv < 2; ++dv)
        #pragma unroll
        for (int c = 0; c < 2; ++c)
            vf[dv][c] = repack(vpk[dv][2*c][0], vpk[dv][2*c][1],
                               vpk[dv][2*c+1][0], vpk[dv][2*c+1][1], src0, src1, hi);

    #pragma unroll
    for (int mtq = 0; mtq < 4; ++mtq) {
        // Q^T B-frag for this token tile
        const bf16x8 qf = repack(qpk[0][mtq][0], qpk[0][mtq][1], qpk[1][mtq][0], qpk[1][mtq][1],
                                 src0, src1, hi);
        // S^T tiles: D[ktok][qtok] = K(A) . Q^T(B)
        f32x4 s[4];
        #pragma unroll
        for (int mtk = 0; mtk < 4; ++mtk) {
            f32x4 z = {0.f, 0.f, 0.f, 0.f};
            s[mtk] = __builtin_amdgcn_mfma_f32_16x16x32_bf16(kf[mtk], qf, z, 0, 0, 0);
        }
        // + bias + mask (pads = -1e30)
        #pragma unroll
        for (int mtk = 0; mtk < 4; ++mtk)
            #pragma unroll
            for (int r = 0; r < 4; ++r) {
                const unsigned u = bmpk[mtq][mtk][r >> 1];
                s[mtk][r] += __uint_as_float((r & 1) ? (u & 0xffff0000u) : (u << 16));
            }
        // softmax over ktok (16 in-lane x 4 lg-groups)
        float mx;
        {
            float m_[4];
            #pragma unroll
            for (int mtk = 0; mtk < 4; ++mtk)
                m_[mtk] = fmaxf(fmaxf(s[mtk][0], s[mtk][1]), fmaxf(s[mtk][2], s[mtk][3]));
            mx = fmaxf(fmaxf(m_[0], m_[1]), fmaxf(m_[2], m_[3]));
        }
        mx = fmaxf(mx, __shfl_xor(mx, 16, 64));
        mx = fmaxf(mx, __shfl_xor(mx, 32, 64));
        float sum;
        {
            float s_[4];
            #pragma unroll
            for (int mtk = 0; mtk < 4; ++mtk) {
                #pragma unroll
                for (int r = 0; r < 4; ++r)
                    s[mtk][r] = __expf(s[mtk][r] - mx);
                s_[mtk] = (s[mtk][0] + s[mtk][1]) + (s[mtk][2] + s[mtk][3]);
            }
            sum = (s_[0] + s_[1]) + (s_[2] + s_[3]);
        }
        sum += __shfl_xor(sum, 16, 64);
        sum += __shfl_xor(sum, 32, 64);
        const float inv = 1.0f / sum;
        // normalize + pack, then P^T B-frags
        unsigned pkv[4][2];
        #pragma unroll
        for (int mtk = 0; mtk < 4; ++mtk) {
            pkv[mtk][0] = pk2(s[mtk][0]*inv, s[mtk][1]*inv);
            pkv[mtk][1] = pk2(s[mtk][2]*inv, s[mtk][3]*inv);
        }
        bf16x8 pa[2];
        #pragma unroll
        for (int c = 0; c < 2; ++c)
            pa[c] = repack(pkv[2*c][0], pkv[2*c][1], pkv[2*c+1][0], pkv[2*c+1][1],
                           src0, src1, hi);
        // PV: ao^T = V^T(A) . P^T(B); write b64 to ao_lds (wave-private columns)
        #pragma unroll
        for (int dv = 0; dv < 2; ++dv) {
            f32x4 o = {0.f, 0.f, 0.f, 0.f};
            o = __builtin_amdgcn_mfma_f32_16x16x32_bf16(vf[dv][0], pa[0], o, 0, 0, 0);
            o = __builtin_amdgcn_mfma_f32_16x16x32_bf16(vf[dv][1], pa[1], o, 0, 0, 0);
            unsigned w0 = pk2(o[0], o[1]);
            unsigned w1 = pk2(o[2], o[3]);
            *(unsigned long long*)(ao_lds + (mtq*16 + lq)*LDA + wv*32 + dv*16 + lg*4) =
                (unsigned long long)w0 | ((unsigned long long)w1 << 32);
        }
    }
    __syncthreads();   // ao complete (the ONLY barrier)

    // ---- Phase 3: out^T = Wp^T(A) . ao^T(B); ao B-frags read via duality ----
    float* ob = out + (size_t)b * (NTOK * CDIM);
    #pragma unroll
    for (int t = 0; t < 2; ++t) {
        const int nto = 2*wv + t;
        bf16x8 wf[4];
        #pragma unroll
        for (int kk = 0; kk < 4; ++kk)
            wf[kk] = *(const bf16x8*)(wb + PROJ_WOFF + (nto*4 + kk)*512 + l*8);
        const f32x4 pbv = *(const f32x4*)(proj_b + nto*16 + lg*4);
        #pragma unroll
        for (int mt = 0; mt < 4; ++mt) {
            f32x4 acc = pbv;
            #pragma unroll
            for (int kk = 0; kk < 4; ++kk) {
                bf16x8 ab = *(const bf16x8*)(ao_lds + (mt*16 + lq)*LDA + kk*32 + lg*8);
                acc = __builtin_amdgcn_mfma_f32_16x16x32_bf16(wf[kk], ab, acc, 0, 0, 0);
            }
            const int tok = mt*16 + lq;
            if (tok < NTOK)
                *(f32x4*)(ob + tok*CDIM + nto*16 + lg*4) = acc;
        }
    }
}

extern "C" void kernel_launch(void* const* d_in, const int* in_sizes, int n_in,
                              void* d_out, int out_size, void* d_ws, size_t ws_size,
                              hipStream_t stream) {
    (void)in_sizes; (void)n_in; (void)out_size; (void)ws_size;
    const float* x          = (const float*)d_in[0];
    const float* mask       = (const float*)d_in[1];
    const float* qkv_w      = (const float*)d_in[2];
    const float* qkv_b      = (const float*)d_in[3];
    const float* proj_w     = (const float*)d_in[4];
    const float* proj_b     = (const float*)d_in[5];
    const float* bias_table = (const float*)d_in[6];
    float* out = (float*)d_out;
    short* wb  = (short*)d_ws;   // 131072 B used

    hipLaunchKernelGGL(prep_w,   dim3(128),  dim3(64),  0, stream, qkv_w, proj_w, wb);
    hipLaunchKernelGGL(win_attn, dim3(4096), dim3(256), 0, stream,
                       x, mask, qkv_b, proj_b, bias_table, wb, out);
}

// Round 10
// 131.153 us; speedup vs baseline: 1.3103x; 1.3103x over previous
//
#include <hip/hip_runtime.h>
#include <hip/hip_bf16.h>

// Swin window attention, fully fused, bf16-MFMA.
// Base = round-8 structure (best: 132.8 us): token-stripe QKV, 32 KB swizzled LDS,
// in-register q/ao, duality phase 3. Round-10 changes target ILP (the measured
// limiter: both pipes <35% busy at 42% occupancy = per-wave serial chains):
//  - phase 2 computes HEAD PAIRS simultaneously (two independent S/softmax/PV
//    chains interleaved at source level -> stalls of one fill with the other).
//  - phase 1 processes nt in PAIRS with all 8 weight frags loaded up front.
//  - launch_bounds(256,4): VGPR cap 128 so the interleaved chains get registers
//    (R8's 48-of-102 proved the compiler serialized for minimal regs).
//  - SCALE folded into prepped Wq (and q-bias at acc-init, off the pack path).
// MFMA 16x16x32 bf16 layouts (validated end-to-end rounds 3/5/6/8):
//   src0 A: lane holds A[lane&15][(lane>>4)*8+j]
//   src1 B: lane holds B[(lane>>4)*8+j][lane&15]
//   D:      lane holds D[(lane>>4)*4+r][lane&15]

typedef __attribute__((ext_vector_type(8))) short bf16x8;
typedef __attribute__((ext_vector_type(4))) float f32x4;

#define NTOK  49
#define CDIM  128
#define NWIN  256
#define SCALE 0.17677669529663687f
#define PROJ_WOFF 49152   // shorts: 96 frags * 512

static __device__ __forceinline__ unsigned pk2(float a, float b) {
    __hip_bfloat162 h = __float22bfloat162_rn(make_float2(a, b));  // low = a, high = b, RNE
    unsigned u; __builtin_memcpy(&u, &h, 4); return u;
}
static __device__ __forceinline__ short bf1(float a) {
    __hip_bfloat16 h = __float2bfloat16(a);
    unsigned short u; __builtin_memcpy(&u, &h, 2); return (short)u;
}
static __device__ __forceinline__ bf16x8 repack(unsigned p00, unsigned p01,
                                                unsigned p10, unsigned p11,
                                                int src0, int src1, bool hi) {
    union { bf16x8 v; unsigned u[4]; } t;
    unsigned a0, a1;
    a0 = __shfl((int)p00, src0, 64); a1 = __shfl((int)p10, src0, 64); t.u[0] = hi ? a1 : a0;
    a0 = __shfl((int)p01, src0, 64); a1 = __shfl((int)p11, src0, 64); t.u[1] = hi ? a1 : a0;
    a0 = __shfl((int)p00, src1, 64); a1 = __shfl((int)p10, src1, 64); t.u[2] = hi ? a1 : a0;
    a0 = __shfl((int)p01, src1, 64); a1 = __shfl((int)p11, src1, 64); t.u[3] = hi ? a1 : a0;
    return t.v;
}

// ---- weight pre-swizzle: per-tile fragments = A-frags of W^T (== B-frags of W) ----
// q-tiles (fid < 32) are pre-scaled by SCALE.
__global__ void prep_w(const float* __restrict__ qkv_w,
                       const float* __restrict__ proj_w,
                       short* __restrict__ wb) {
    const int fid = blockIdx.x;     // 0..127 (96 qkv + 32 proj)
    const int l   = threadIdx.x;    // 0..63
    const int lq = l & 15, lg = l >> 4;
    bf16x8 v;
    if (fid < 96) {
        const int nt = fid >> 2, kk = fid & 3;
        const float s = (fid < 32) ? SCALE : 1.0f;
        #pragma unroll
        for (int j = 0; j < 8; ++j)
            v[j] = bf1(qkv_w[(kk*32 + lg*8 + j)*384 + nt*16 + lq] * s);
        *(bf16x8*)(wb + fid*512 + l*8) = v;
    } else {
        const int f2 = fid - 96;
        const int nt = f2 >> 2, kk = f2 & 3;
        #pragma unroll
        for (int j = 0; j < 8; ++j)
            v[j] = bf1(proj_w[(kk*32 + lg*8 + j)*128 + nt*16 + lq]);
        *(bf16x8*)(wb + PROJ_WOFF + f2*512 + l*8) = v;
    }
}

__global__ __launch_bounds__(256, 4)
void win_attn(const float* __restrict__ x,
              const float* __restrict__ mask,
              const float* __restrict__ qkv_b,
              const float* __restrict__ proj_b,
              const float* __restrict__ bias_table,
              const short* __restrict__ wb,
              float* __restrict__ out) {
    // unpadded, XOR-swizzled in 16B units: phys = row*128 + ((u ^ (row&7))<<3) + low
    __shared__ __align__(16) short kl[64 * 128];    // k            (16384 B)
    __shared__ __align__(16) short vt[128 * 64];    // v transposed (16384 B)

    const int b    = blockIdx.x;
    const int tid  = threadIdx.x;
    const int l    = tid & 63;
    const int wave = tid >> 6;
    const int lq   = l & 15, lg = l >> 4;
    const int m0   = wave * 16;
    const int qtok = m0 + lq;

    // ---- Phase 0: own-stripe x^T B-frags, global -> regs (bf16). Row-clamp pads. ----
    const float* xb = x + (size_t)b * (NTOK * CDIM);
    bf16x8 xa[4];
    {
        int row = qtok; if (row > 48) row = 48;
        const float* pr = xb + row*CDIM + lg*8;
        #pragma unroll
        for (int kk = 0; kk < 4; ++kk) {
            float4 f0 = *(const float4*)(pr + kk*32);
            float4 f1 = *(const float4*)(pr + kk*32 + 4);
            union { bf16x8 v; unsigned u[4]; } t;
            t.u[0] = pk2(f0.x, f0.y);
            t.u[1] = pk2(f0.z, f0.w);
            t.u[2] = pk2(f1.x, f1.y);
            t.u[3] = pk2(f1.z, f1.w);
            xa[kk] = t.v;
        }
    }

    // ---- Phase 1: all 24 wcol-tiles for own token stripe, processed in PAIRS.
    //      q->regs, k/v->swizzled LDS. 8 loads issued up front per pair. ----
    unsigned qpk[8][2];   // qpk[nt][w]: q[qtok][nt*16+lg*4+{2w,2w+1}] (pre-scaled)
    #pragma unroll
    for (int np = 0; np < 12; ++np) {
        const int n0 = 2*np, n1 = 2*np + 1;
        bf16x8 wfA[4], wfB[4];
        #pragma unroll
        for (int kk = 0; kk < 4; ++kk)
            wfA[kk] = *(const bf16x8*)(wb + (n0*4 + kk)*512 + l*8);
        #pragma unroll
        for (int kk = 0; kk < 4; ++kk)
            wfB[kk] = *(const bf16x8*)(wb + (n1*4 + kk)*512 + l*8);
        f32x4 aA = *(const f32x4*)(qkv_b + n0*16 + lg*4);
        f32x4 aB = *(const f32x4*)(qkv_b + n1*16 + lg*4);
        if (n0 < 8) { aA = aA * SCALE; aB = aB * SCALE; }   // weights pre-scaled
        #pragma unroll
        for (int kk = 0; kk < 4; ++kk)
            aA = __builtin_amdgcn_mfma_f32_16x16x32_bf16(wfA[kk], xa[kk], aA, 0, 0, 0);
        #pragma unroll
        for (int kk = 0; kk < 4; ++kk)
            aB = __builtin_amdgcn_mfma_f32_16x16x32_bf16(wfB[kk], xa[kk], aB, 0, 0, 0);
        // stores: D lane holds (wcol = nt*16+lg*4+r, tok = qtok)
        #pragma unroll
        for (int e = 0; e < 2; ++e) {
            const int nt = 2*np + e;
            const f32x4 acc = e ? aB : aA;
            if (nt < 8) {                                // q -> registers
                qpk[nt][0] = pk2(acc[0], acc[1]);
                qpk[nt][1] = pk2(acc[2], acc[3]);
            } else if (nt < 16) {                        // k -> kl swizzled b64
                unsigned w0 = pk2(acc[0], acc[1]);
                unsigned w1 = pk2(acc[2], acc[3]);
                const int ub  = (nt - 8)*2 + (lg >> 1);
                const int off = qtok*128 + ((ub ^ (qtok & 7)) << 3) + (lg & 1)*4;
                *(unsigned long long*)(kl + off) =
                    (unsigned long long)w0 | ((unsigned long long)w1 << 32);
            } else {                                     // v -> vt[dim][tok] swizzled b16
                #pragma unroll
                for (int r = 0; r < 4; ++r) {
                    const int dim = (nt - 16)*16 + lg*4 + r;
                    vt[dim*64 + (((qtok >> 3) ^ (dim & 7)) << 3) + (qtok & 7)] = bf1(acc[r]);
                }
            }
        }
    }

    // ---- Phase 1c: bias+mask hoist -> bmpk (4 heads bf16-packed; pads = -1e30) ----
    const float* mwin = mask + (size_t)(b & (NWIN - 1)) * (NTOK * NTOK);
    unsigned bmpk[4][4][2];
    {
        const unsigned NEG = pk2(-1e30f, -1e30f);
        #pragma unroll
        for (int nt = 0; nt < 4; ++nt)
            #pragma unroll
            for (int r = 0; r < 4; ++r) {
                const int kt = nt*16 + lg*4 + r;
                if (qtok < NTOK && kt < NTOK) {
                    const int ridx = (qtok/7 - kt/7 + 6)*13 + (qtok%7 - kt%7 + 6);
                    const f32x4 b4 = *(const f32x4*)(bias_table + ridx*4);
                    const float mv = mwin[qtok*NTOK + kt];
                    bmpk[nt][r][0] = pk2(b4[0] + mv, b4[1] + mv);
                    bmpk[nt][r][1] = pk2(b4[2] + mv, b4[3] + mv);
                } else {
                    bmpk[nt][r][0] = NEG; bmpk[nt][r][1] = NEG;
                }
            }
    }
    __syncthreads();   // kl/vt complete (the ONLY barrier)

    // ---- Phase 2: attention in HEAD PAIRS (two independent chains interleaved) ----
    const int src0 = lq + 16*((2*lg + 0) & 3);
    const int src1 = lq + 16*((2*lg + 1) & 3);
    const bool hi  = (lg >> 1);
    unsigned aopk[8][2];                             // ao[qtok][tile*16+lg*4+{..}], tile=2h+dn

    #pragma unroll
    for (int hp = 0; hp < 2; ++hp) {
        const int h0 = 2*hp, h1 = h0 + 1;
        const bf16x8 qfA = repack(qpk[2*h0][0], qpk[2*h0][1], qpk[2*h0+1][0], qpk[2*h0+1][1],
                                  src0, src1, hi);
        const bf16x8 qfB = repack(qpk[2*h1][0], qpk[2*h1][1], qpk[2*h1+1][0], qpk[2*h1+1][1],
                                  src0, src1, hi);
        // S^T tiles for both heads: D[ktok][qtok] = K(A) . Q^T(B)
        f32x4 sA[4], sB[4];
        #pragma unroll
        for (int nt = 0; nt < 4; ++nt) {
            const int krow = nt*16 + lq;
            bf16x8 kfA = *(const bf16x8*)(kl + krow*128 + (((h0*4 + lg) ^ (krow & 7)) << 3));
            bf16x8 kfB = *(const bf16x8*)(kl + krow*128 + (((h1*4 + lg) ^ (krow & 7)) << 3));
            f32x4 z = {0.f, 0.f, 0.f, 0.f};
            sA[nt] = __builtin_amdgcn_mfma_f32_16x16x32_bf16(kfA, qfA, z, 0, 0, 0);
            sB[nt] = __builtin_amdgcn_mfma_f32_16x16x32_bf16(kfB, qfB, z, 0, 0, 0);
        }
        // + bias+mask: head h0 = low short of word hp, h1 = high short
        #pragma unroll
        for (int nt = 0; nt < 4; ++nt)
            #pragma unroll
            for (int r = 0; r < 4; ++r) {
                const unsigned u = bmpk[nt][r][hp];
                sA[nt][r] += __uint_as_float(u << 16);
                sB[nt][r] += __uint_as_float(u & 0xffff0000u);
            }
        // softmax, both heads interleaved (independent trees)
        float mxA, mxB;
        {
            float a_[4], b_[4];
            #pragma unroll
            for (int nt = 0; nt < 4; ++nt) {
                a_[nt] = fmaxf(fmaxf(sA[nt][0], sA[nt][1]), fmaxf(sA[nt][2], sA[nt][3]));
                b_[nt] = fmaxf(fmaxf(sB[nt][0], sB[nt][1]), fmaxf(sB[nt][2], sB[nt][3]));
            }
            mxA = fmaxf(fmaxf(a_[0], a_[1]), fmaxf(a_[2], a_[3]));
            mxB = fmaxf(fmaxf(b_[0], b_[1]), fmaxf(b_[2], b_[3]));
        }
        mxA = fmaxf(mxA, __shfl_xor(mxA, 16, 64));
        mxB = fmaxf(mxB, __shfl_xor(mxB, 16, 64));
        mxA = fmaxf(mxA, __shfl_xor(mxA, 32, 64));
        mxB = fmaxf(mxB, __shfl_xor(mxB, 32, 64));
        float sumA, sumB;
        {
            float a_[4], b_[4];
            #pragma unroll
            for (int nt = 0; nt < 4; ++nt) {
                #pragma unroll
                for (int r = 0; r < 4; ++r) {
                    sA[nt][r] = __expf(sA[nt][r] - mxA);
                    sB[nt][r] = __expf(sB[nt][r] - mxB);
                }
                a_[nt] = (sA[nt][0] + sA[nt][1]) + (sA[nt][2] + sA[nt][3]);
                b_[nt] = (sB[nt][0] + sB[nt][1]) + (sB[nt][2] + sB[nt][3]);
            }
            sumA = (a_[0] + a_[1]) + (a_[2] + a_[3]);
            sumB = (b_[0] + b_[1]) + (b_[2] + b_[3]);
        }
        sumA += __shfl_xor(sumA, 16, 64);
        sumB += __shfl_xor(sumB, 16, 64);
        sumA += __shfl_xor(sumA, 32, 64);
        sumB += __shfl_xor(sumB, 32, 64);
        const float invA = 1.0f / sumA;
        const float invB = 1.0f / sumB;
        // normalize + pack + repack to P^T B-frags, both heads
        unsigned pkvA[4][2], pkvB[4][2];
        #pragma unroll
        for (int nt = 0; nt < 4; ++nt) {
            pkvA[nt][0] = pk2(sA[nt][0]*invA, sA[nt][1]*invA);
            pkvA[nt][1] = pk2(sA[nt][2]*invA, sA[nt][3]*invA);
            pkvB[nt][0] = pk2(sB[nt][0]*invB, sB[nt][1]*invB);
            pkvB[nt][1] = pk2(sB[nt][2]*invB, sB[nt][3]*invB);
        }
        bf16x8 paA[2], paB[2];
        #pragma unroll
        for (int c = 0; c < 2; ++c) {
            paA[c] = repack(pkvA[2*c][0], pkvA[2*c][1], pkvA[2*c+1][0], pkvA[2*c+1][1],
                            src0, src1, hi);
            paB[c] = repack(pkvB[2*c][0], pkvB[2*c][1], pkvB[2*c+1][0], pkvB[2*c+1][1],
                            src0, src1, hi);
        }
        // PV both heads: ao^T = V^T(A) . P^T(B)
        #pragma unroll
        for (int dn = 0; dn < 2; ++dn) {
            f32x4 oA = {0.f, 0.f, 0.f, 0.f};
            f32x4 oB = {0.f, 0.f, 0.f, 0.f};
            #pragma unroll
            for (int kk = 0; kk < 2; ++kk) {
                const int dimA = h0*32 + dn*16 + lq;
                const int dimB = h1*32 + dn*16 + lq;
                bf16x8 vfA = *(const bf16x8*)(vt + dimA*64 + (((kk*4 + lg) ^ (dimA & 7)) << 3));
                bf16x8 vfB = *(const bf16x8*)(vt + dimB*64 + (((kk*4 + lg) ^ (dimB & 7)) << 3));
                oA = __builtin_amdgcn_mfma_f32_16x16x32_bf16(vfA, paA[kk], oA, 0, 0, 0);
                oB = __builtin_amdgcn_mfma_f32_16x16x32_bf16(vfB, paB[kk], oB, 0, 0, 0);
            }
            aopk[2*h0 + dn][0] = pk2(oA[0], oA[1]);
            aopk[2*h0 + dn][1] = pk2(oA[2], oA[3]);
            aopk[2*h1 + dn][0] = pk2(oB[0], oB[1]);
            aopk[2*h1 + dn][1] = pk2(oB[2], oB[3]);
        }
    }

    // ---- Phase 3: out^T = Wp^T(A) . ao^T(B); B-frag == A-frag of ao (duality) ----
    bf16x8 ab[4];
    #pragma unroll
    for (int kk = 0; kk < 4; ++kk)
        ab[kk] = repack(aopk[2*kk][0], aopk[2*kk][1], aopk[2*kk+1][0], aopk[2*kk+1][1],
                        src0, src1, hi);
    float* ob = out + (size_t)b * (NTOK * CDIM);
    #pragma unroll
    for (int nt = 0; nt < 8; ++nt) {
        bf16x8 wf[4];
        #pragma unroll
        for (int kk = 0; kk < 4; ++kk)
            wf[kk] = *(const bf16x8*)(wb + PROJ_WOFF + (nt*4 + kk)*512 + l*8);
        f32x4 acc = *(const f32x4*)(proj_b + nt*16 + lg*4);        // D rows = ocols
        #pragma unroll
        for (int kk = 0; kk < 4; ++kk)
            acc = __builtin_amdgcn_mfma_f32_16x16x32_bf16(wf[kk], ab[kk], acc, 0, 0, 0);
        // D: (ocol = nt*16+lg*4+r, tok = qtok) -> out[tok][ocol], r consecutive -> f32x4
        if (qtok < NTOK)
            *(f32x4*)(ob + qtok*CDIM + nt*16 + lg*4) = acc;
    }
}

extern "C" void kernel_launch(void* const* d_in, const int* in_sizes, int n_in,
                              void* d_out, int out_size, void* d_ws, size_t ws_size,
                              hipStream_t stream) {
    (void)in_sizes; (void)n_in; (void)out_size; (void)ws_size;
    const float* x          = (const float*)d_in[0];
    const float* mask       = (const float*)d_in[1];
    const float* qkv_w      = (const float*)d_in[2];
    const float* qkv_b      = (const float*)d_in[3];
    const float* proj_w     = (const float*)d_in[4];
    const float* proj_b     = (const float*)d_in[5];
    const float* bias_table = (const float*)d_in[6];
    float* out = (float*)d_out;
    short* wb  = (short*)d_ws;   // 131072 B used

    hipLaunchKernelGGL(prep_w,   dim3(128),  dim3(64),  0, stream, qkv_w, proj_w, wb);
    hipLaunchKernelGGL(win_attn, dim3(4096), dim3(256), 0, stream,
                       x, mask, qkv_b, proj_b, bias_table, wb, out);
}